// Round 5
// baseline (5586.486 us; speedup 1.0000x reference)
//
#include <hip/hip_runtime.h>
#include <hip/hip_bf16.h>

// Shapes: B=128, L=512, D=13, H=128, G=4H=512.
typedef __attribute__((ext_vector_type(8))) short bf16x8;
typedef __attribute__((ext_vector_type(4))) float f32x4;

__device__ __forceinline__ float bfbits(unsigned short u) {
  return __uint_as_float(((unsigned int)u) << 16);
}
__device__ __forceinline__ float sigf(float x) { return 1.f / (1.f + __expf(-x)); }
__device__ __forceinline__ float tanhf_(float x) {
  x = fminf(15.f, fmaxf(-15.f, x));
  float t = __expf(2.f * x);
  return (t - 1.f) / (t + 1.f);
}
// Gate-column permutation: pg = w*32 + ty*8 + u  <->  orig = ty*128 + w*8 + u.
// (wave w owns all 4 gate types of h-columns [w*8, w*8+8).)
__device__ __forceinline__ int permorig(int pg) {
  return ((pg >> 3) & 3) * 128 + (pg >> 5) * 8 + (pg & 7);
}

// ---------------------------------------------------------------------------
// Weight prep (all outputs in PERMUTED gate order):
//   whht[lay][d][k][pg] fp32; wihbf (21|31|32) bf16 [d][pg][K]; bsum[lay][d][pg].
// ---------------------------------------------------------------------------
__global__ __launch_bounds__(256) void wconv(
    const float* whh0, const float* whh1, const float* whh2, const float* whh3, const float* whh4,
    const float* wi21, const float* wi31, const float* wi32,
    const float* bi0, const float* bh0, const float* bi1, const float* bh1,
    const float* bi2, const float* bh2, const float* bi3, const float* bh3,
    const float* bi4, const float* bh4,
    float* whht, __hip_bfloat16* wihbf, float* bsum)
{
  int tid = blockIdx.x * 256 + threadIdx.x;
  if (tid < 5 * 131072) {                       // whht: [5][2][128][512]
    int lay = tid / 131072, r = tid % 131072;
    const float* src = lay == 0 ? whh0 : lay == 1 ? whh1 : lay == 2 ? whh2 : lay == 3 ? whh3 : whh4;
    int d = r >> 16;
    int k = (r >> 9) & 127;
    int pg = r & 511;
    whht[tid] = src[((size_t)d * 512 + permorig(pg)) * 128 + k];
    return;
  }
  int t2 = tid - 5 * 131072;
  if (t2 < 1048576) {                           // wihbf: w21(K256) | w31(K512) | w32(K256)
    const float* src; int ci, K;
    if (t2 < 262144)      { src = wi21; ci = t2;          K = 256; }
    else if (t2 < 786432) { src = wi31; ci = t2 - 262144; K = 512; }
    else                  { src = wi32; ci = t2 - 786432; K = 256; }
    int d = ci / (512 * K), rr = ci % (512 * K);
    int pg = rr / K, k = rr % K;
    wihbf[t2] = __float2bfloat16(src[((size_t)d * 512 + permorig(pg)) * K + k]);
    return;
  }
  int t3 = t2 - 1048576;
  if (t3 < 5120) {                              // bsum: [5][2][512] permuted
    int lay = t3 >> 10, idx = t3 & 1023;
    int d = idx >> 9, pg = idx & 511;
    const float* bi = lay == 0 ? bi0 : lay == 1 ? bi1 : lay == 2 ? bi2 : lay == 3 ? bi3 : bi4;
    const float* bh = lay == 0 ? bh0 : lay == 1 ? bh1 : lay == 2 ? bh2 : lay == 3 ? bh3 : bh4;
    int o = d * 512 + permorig(pg);
    bsum[t3] = bi[o] + bh[o];
  }
}

// ---------------------------------------------------------------------------
// K=13 projection -> xg[d][g][t][row16][pg] (permuted cols, scan-tiled layout).
// ---------------------------------------------------------------------------
__global__ __launch_bounds__(256) void proj13(
    const float* __restrict__ x, const float* __restrict__ wih,
    const float* __restrict__ bsum, __hip_bfloat16* __restrict__ xg)
{
  int tid = blockIdx.x * 256 + threadIdx.x;   // 2^26 threads
  int col = tid & 511;
  int row16 = (tid >> 9) & 15;
  int t = (tid >> 13) & 511;
  int g = (tid >> 22) & 7;
  int d = tid >> 25;
  int b = g * 16 + row16;
  const float* xp = x + ((size_t)b * 512 + t) * 13;
  const float* wp = wih + ((size_t)d * 512 + permorig(col)) * 13;
  float acc = bsum[d * 512 + col];
#pragma unroll
  for (int k = 0; k < 13; ++k) acc += xp[k] * wp[k];
  xg[tid] = __float2bfloat16(acc);
}

// ---------------------------------------------------------------------------
// bf16 MFMA projection GEMM; epilogue writes the scan-tiled xg layout.
// ---------------------------------------------------------------------------
__global__ __launch_bounds__(256) void projM(
    const __hip_bfloat16* __restrict__ A, int lda, int K,
    const __hip_bfloat16* __restrict__ Bw,
    const float* __restrict__ bsum,
    __hip_bfloat16* __restrict__ out)
{
  int d = blockIdx.z;
  const __hip_bfloat16* Bp = Bw + (size_t)d * 512 * K;
  const float* bs = bsum + d * 512;
  __hip_bfloat16* op = out + (size_t)d * 8 * 512 * 16 * 512;
  int m0 = blockIdx.y * 128, n0 = blockIdx.x * 128;
  __shared__ __align__(16) __hip_bfloat16 As[128][32];
  __shared__ __align__(16) __hip_bfloat16 Bs[128][32];
  int tid = threadIdx.x, w = tid >> 6, l = tid & 63;
  int wm = (w >> 1) * 64, wn = (w & 1) * 64;
  f32x4 acc[4][4];
#pragma unroll
  for (int mi = 0; mi < 4; ++mi)
#pragma unroll
    for (int ni = 0; ni < 4; ++ni) acc[mi][ni] = (f32x4){0.f, 0.f, 0.f, 0.f};
  int srow = tid >> 2, sc = tid & 3;
  for (int k0 = 0; k0 < K; k0 += 32) {
#pragma unroll
    for (int p = 0; p < 2; ++p) {
      int row = p * 64 + srow;
      int slot = sc ^ (row & 3);
      uint4 va = *(const uint4*)(A + (size_t)(m0 + row) * lda + k0 + sc * 8);
      *(uint4*)(&As[row][slot * 8]) = va;
      uint4 vb = *(const uint4*)(Bp + (size_t)(n0 + row) * K + k0 + sc * 8);
      *(uint4*)(&Bs[row][slot * 8]) = vb;
    }
    __syncthreads();
    bf16x8 af[4], bfr[4];
#pragma unroll
    for (int mi = 0; mi < 4; ++mi) {
      int row = wm + mi * 16 + (l & 15);
      int slot = (l >> 4) ^ (row & 3);
      af[mi] = *(const bf16x8*)(&As[row][slot * 8]);
    }
#pragma unroll
    for (int ni = 0; ni < 4; ++ni) {
      int row = wn + ni * 16 + (l & 15);
      int slot = (l >> 4) ^ (row & 3);
      bfr[ni] = *(const bf16x8*)(&Bs[row][slot * 8]);
    }
#pragma unroll
    for (int mi = 0; mi < 4; ++mi)
#pragma unroll
      for (int ni = 0; ni < 4; ++ni)
        acc[mi][ni] = __builtin_amdgcn_mfma_f32_16x16x32_bf16(af[mi], bfr[ni], acc[mi][ni], 0, 0, 0);
    __syncthreads();
  }
#pragma unroll
  for (int ni = 0; ni < 4; ++ni) {
    int col = n0 + wn + ni * 16 + (l & 15);
    float bsv = bs[col];
#pragma unroll
    for (int mi = 0; mi < 4; ++mi) {
#pragma unroll
      for (int q = 0; q < 4; ++q) {
        int row = m0 + wm + mi * 16 + (l >> 4) * 4 + q;   // = b*512 + t
        int b = row >> 9, t = row & 511;
        size_t oidx = (((size_t)(b >> 4) * 512 + t) * 16 + (b & 15)) * 512 + col;
        op[oidx] = __float2bfloat16(acc[mi][ni][q] + bsv);
      }
    }
  }
}

// ---------------------------------------------------------------------------
// LSTM scan v4 (MFMA-batched): block = (batch-group g of 16 rows, dir d).
// 16 waves; wave w owns permuted gate cols [w*32, w*32+32) = {i,f,g,o}x8 hcols.
// W split Whi+Wlo bf16 in register fragments (AGPR-friendly: only MFMA reads
// them). h-tile bf16 in LDS (4 KB, double-buffered, fragment layout).
// Gate exchange via 4 shfl_xor(8). xg is the MFMA C-input (prefetched).
// One barrier per step.
// ---------------------------------------------------------------------------
__global__ __launch_bounds__(1024, 4) void scan4(
    const __hip_bfloat16* __restrict__ xg,   // [2][8][512][16][512] this layer
    const float* __restrict__ whht,          // [2][128][512] this layer, permuted
    __hip_bfloat16* __restrict__ yout, int ycols, int ycoloff,
    float* __restrict__ y3out, int y3off, int maxpool)
{
  const int g = blockIdx.x, d = blockIdx.y;
  const int tid = threadIdx.x, w = tid >> 6, l = tid & 63;
  const int sub = l >> 4;          // 0..3 (k-subgroup / row-group)
  const int u = l & 15;
  const int lowu = (u < 8) ? 1 : 0;
  __shared__ __align__(16) __hip_bfloat16 HT[2][2048];   // [kb][sub][row][8e]

  // --- recurrent W fragments: hi/lo bf16 split, [n16*4+kb] ---
  bf16x8 whi[8], wlo[8];
  {
    const float* wp = whht + (size_t)d * 65536;
#pragma unroll
    for (int n16 = 0; n16 < 2; ++n16) {
#pragma unroll
      for (int kb = 0; kb < 4; ++kb) {
        int pg = w * 32 + n16 * 16 + u;
        bf16x8 ph, pl;
#pragma unroll
        for (int e = 0; e < 8; ++e) {
          int k = kb * 32 + sub * 8 + e;
          float v = wp[(size_t)k * 512 + pg];
          __hip_bfloat16 hb = __float2bfloat16(v);
          float r = v - __bfloat162float(hb);
          __hip_bfloat16 lb = __float2bfloat16(r);
          ph[e] = *reinterpret_cast<short*>(&hb);
          pl[e] = *reinterpret_cast<short*>(&lb);
        }
        whi[n16 * 4 + kb] = ph;
        wlo[n16 * 4 + kb] = pl;
      }
    }
  }
#pragma unroll
  for (int i = 0; i < 8; ++i) {
    asm volatile("" : "+v"(whi[i]));
    asm volatile("" : "+v"(wlo[i]));
  }

  // --- xg addressing: 8 elements per thread per step, [n16][q] order ---
  const unsigned short* xb = (const unsigned short*)xg + (size_t)(d * 8 + g) * 4194304;
  int xoff[8];
#pragma unroll
  for (int n16 = 0; n16 < 2; ++n16)
#pragma unroll
    for (int q = 0; q < 4; ++q)
      xoff[n16 * 4 + q] = (sub * 4 + q) * 512 + w * 32 + n16 * 16 + u;

  // zero h(0)
  HT[0][tid] = __float2bfloat16(0.f);
  HT[0][tid + 1024] = __float2bfloat16(0.f);

  float c0 = 0.f, c1 = 0.f, m0r = -1e30f, m1r = -1e30f;
  int cur = 0;
  int tt0 = d ? 511 : 0;
  unsigned short pf[8];
#pragma unroll
  for (int i = 0; i < 8; ++i) pf[i] = xb[(size_t)tt0 * 8192 + xoff[i]];
  __syncthreads();

  for (int t = 0; t < 512; ++t) {
    int tt = d ? 511 - t : t;
    int tn = (t + 1 < 512) ? t + 1 : 511;
    int ttn = d ? 511 - tn : tn;
    unsigned short pn[8];
#pragma unroll
    for (int i = 0; i < 8; ++i) pn[i] = xb[(size_t)ttn * 8192 + xoff[i]];   // prefetch

    // A fragments (h-tile) for all 4 k-blocks
    bf16x8 af[4];
#pragma unroll
    for (int kb = 0; kb < 4; ++kb)
      af[kb] = *(const bf16x8*)(&HT[cur][kb * 512 + sub * 128 + u * 8]);

    f32x4 a0 = (f32x4){bfbits(pf[0]), bfbits(pf[1]), bfbits(pf[2]), bfbits(pf[3])};
    f32x4 a1 = (f32x4){bfbits(pf[4]), bfbits(pf[5]), bfbits(pf[6]), bfbits(pf[7])};
#pragma unroll
    for (int kb = 0; kb < 4; ++kb) {
      a0 = __builtin_amdgcn_mfma_f32_16x16x32_bf16(af[kb], whi[kb],     a0, 0, 0, 0);
      a0 = __builtin_amdgcn_mfma_f32_16x16x32_bf16(af[kb], wlo[kb],     a0, 0, 0, 0);
      a1 = __builtin_amdgcn_mfma_f32_16x16x32_bf16(af[kb], whi[4 + kb], a1, 0, 0, 0);
      a1 = __builtin_amdgcn_mfma_f32_16x16x32_bf16(af[kb], wlo[4 + kb], a1, 0, 0, 0);
    }
    // a0 = i (u<8) / f (u>=8); a1 = g (u<8) / o (u>=8), rows sub*4+q.
    // Exchange across lane pairs (u <-> u+8): lane u<8 keeps rows {0,1},
    // receives f,o for them; lane u>=8 keeps rows {2,3}, receives i,g.
    float e1 = __shfl_xor(lowu ? a0[2] : a0[0], 8);
    float e2 = __shfl_xor(lowu ? a0[3] : a0[1], 8);
    float e3 = __shfl_xor(lowu ? a1[2] : a1[0], 8);
    float e4 = __shfl_xor(lowu ? a1[3] : a1[1], 8);
    float gi0 = lowu ? a0[0] : e1,  gf0 = lowu ? e1 : a0[2];
    float gg0 = lowu ? a1[0] : e3,  go0 = lowu ? e3 : a1[2];
    float gi1 = lowu ? a0[1] : e2,  gf1 = lowu ? e2 : a0[3];
    float gg1 = lowu ? a1[1] : e4,  go1 = lowu ? e4 : a1[3];

    c0 = sigf(gf0) * c0 + sigf(gi0) * tanhf_(gg0);
    float h0 = sigf(go0) * tanhf_(c0);
    c1 = sigf(gf1) * c1 + sigf(gi1) * tanhf_(gg1);
    float h1 = sigf(go1) * tanhf_(c1);

    int r0 = sub * 4 + (lowu ? 0 : 2);
    int hcol = w * 8 + (u & 7);
    int widx = w * 128 + r0 * 8 + (u & 7);
    __hip_bfloat16 hb0 = __float2bfloat16(h0);
    __hip_bfloat16 hb1 = __float2bfloat16(h1);
    HT[cur ^ 1][widx] = hb0;
    HT[cur ^ 1][widx + 8] = hb1;      // row r0+1
    if (maxpool) { m0r = fmaxf(m0r, h0); m1r = fmaxf(m1r, h1); }
    __syncthreads();
    if (!maxpool) {
      // coalesced-ish y write from the completed h-tile
      int idx = 2 * tid;
      unsigned v = *(const unsigned*)(&HT[cur ^ 1][idx]);
      int row = (idx >> 3) & 15;
      int hc = (idx >> 7) * 8 + (idx & 7);
      int b = g * 16 + row;
      __hip_bfloat16* yp = yout + ((size_t)b * 512 + tt) * ycols + ycoloff + d * 128 + hc;
      *(unsigned*)yp = v;
    }
#pragma unroll
    for (int i = 0; i < 8; ++i) pf[i] = pn[i];
    cur ^= 1;
  }
  if (maxpool) {
    int r0 = sub * 4 + (lowu ? 0 : 2);
    int hcol = w * 8 + (u & 7);
    int bse = y3off + d * 128 + hcol;
    y3out[(size_t)(g * 16 + r0) * 512 + bse] = m0r;
    y3out[(size_t)(g * 16 + r0 + 1) * 512 + bse] = m1r;
  }
}

// ---------------------------------------------------------------------------
// Head: y4 = selu(y3 @ l4w^T + l4b); out = sigmoid(y4 @ fcw^T + fcb).
// ---------------------------------------------------------------------------
__global__ __launch_bounds__(256) void head(
    const float* __restrict__ y3, const float* __restrict__ l4w,
    const float* __restrict__ l4b, const float* __restrict__ fcw,
    const float* __restrict__ fcb, float* __restrict__ outp)
{
  int b = blockIdx.x, t = threadIdx.x;
  __shared__ float row[512];
  __shared__ float y4[128];
  row[t] = y3[(size_t)b * 512 + t];
  row[t + 256] = y3[(size_t)b * 512 + t + 256];
  __syncthreads();
  if (t < 128) {
    float acc = l4b[t];
    const float* wr = l4w + (size_t)t * 512;
    for (int k = 0; k < 512; ++k) acc += row[k] * wr[k];
    const float scale = 1.0507009873554804934193349852946f;
    const float alpha = 1.6732632423543772848170429916717f;
    y4[t] = acc > 0.f ? scale * acc : scale * alpha * (__expf(acc) - 1.f);
  }
  __syncthreads();
  if (t < 2) {
    float acc = fcb[t];
    const float* wr = fcw + (size_t)t * 128;
    for (int k = 0; k < 128; ++k) acc += y4[k] * wr[k];
    outp[b * 2 + t] = 1.f / (1.f + __expf(-acc));
  }
}

extern "C" void kernel_launch(void* const* d_in, const int* in_sizes, int n_in,
                              void* d_out, int out_size, void* d_ws, size_t ws_size,
                              hipStream_t stream) {
  (void)in_sizes; (void)n_in; (void)out_size; (void)ws_size;
  const float* x     = (const float*)d_in[0];
  const float* Wih1  = (const float*)d_in[1];
  const float* Whh1  = (const float*)d_in[2];
  const float* bih1  = (const float*)d_in[3];
  const float* bhh1  = (const float*)d_in[4];
  const float* Wih21 = (const float*)d_in[5];
  const float* Whh21 = (const float*)d_in[6];
  const float* bih21 = (const float*)d_in[7];
  const float* bhh21 = (const float*)d_in[8];
  const float* Wih22 = (const float*)d_in[9];
  const float* Whh22 = (const float*)d_in[10];
  const float* bih22 = (const float*)d_in[11];
  const float* bhh22 = (const float*)d_in[12];
  const float* Wih31 = (const float*)d_in[13];
  const float* Whh31 = (const float*)d_in[14];
  const float* bih31 = (const float*)d_in[15];
  const float* bhh31 = (const float*)d_in[16];
  const float* Wih32 = (const float*)d_in[17];
  const float* Whh32 = (const float*)d_in[18];
  const float* bih32 = (const float*)d_in[19];
  const float* bhh32 = (const float*)d_in[20];
  const float* l4w   = (const float*)d_in[21];
  const float* l4b   = (const float*)d_in[22];
  const float* fcw   = (const float*)d_in[23];
  const float* fcb   = (const float*)d_in[24];

  char* ws = (char*)d_ws;
  __hip_bfloat16* xg    = (__hip_bfloat16*)(ws);               // 134217728 B
  __hip_bfloat16* y1    = (__hip_bfloat16*)(ws + 134217728);   // 33554432 B
  __hip_bfloat16* y2    = (__hip_bfloat16*)(ws + 167772160);   // 67108864 B
  float*          y3    = (float*)(ws + 234881024);            // 262144 B
  __hip_bfloat16* wihbf = (__hip_bfloat16*)(ws + 235143168);   // 2097152 B
  float*          bsum  = (float*)(ws + 237240320);            // 20480 B
  float*          whht  = (float*)(ws + 237260800);            // 2621440 B -> ~239.9 MB

  wconv<<<6677, 256, 0, stream>>>(Whh1, Whh21, Whh22, Whh31, Whh32,
                                  Wih21, Wih31, Wih32,
                                  bih1, bhh1, bih21, bhh21, bih22, bhh22,
                                  bih31, bhh31, bih32, bhh32,
                                  whht, wihbf, bsum);
  // layer 1: x -> y1
  proj13<<<262144, 256, 0, stream>>>(x, Wih1, bsum + 0 * 1024, xg);
  scan4<<<dim3(8, 2), 1024, 0, stream>>>(xg, whht + 0 * 131072, y1, 256, 0, nullptr, 0, 0);
  // layer 22: x -> y2 cols 256..511
  proj13<<<262144, 256, 0, stream>>>(x, Wih22, bsum + 2 * 1024, xg);
  scan4<<<dim3(8, 2), 1024, 0, stream>>>(xg, whht + 2 * 131072, y2, 512, 256, nullptr, 0, 0);
  // layer 21: y1 -> y2 cols 0..255
  projM<<<dim3(4, 512, 2), 256, 0, stream>>>(y1, 256, 256, wihbf + 0, bsum + 1 * 1024, xg);
  scan4<<<dim3(8, 2), 1024, 0, stream>>>(xg, whht + 1 * 131072, y2, 512, 0, nullptr, 0, 0);
  // layer 31: y2 (K=512) -> y3 cols 0..255 (maxpool)
  projM<<<dim3(4, 512, 2), 256, 0, stream>>>(y2, 512, 512, wihbf + 262144, bsum + 3 * 1024, xg);
  scan4<<<dim3(8, 2), 1024, 0, stream>>>(xg, whht + 3 * 131072, nullptr, 0, 0, y3, 0, 1);
  // layer 32: y21 (= y2 cols 0..255, K=256) -> y3 cols 256..511 (maxpool)
  projM<<<dim3(4, 512, 2), 256, 0, stream>>>(y2, 512, 256, wihbf + 786432, bsum + 4 * 1024, xg);
  scan4<<<dim3(8, 2), 1024, 0, stream>>>(xg, whht + 4 * 131072, nullptr, 0, 0, y3, 256, 1);
  // head
  head<<<128, 256, 0, stream>>>(y3, l4w, l4b, fcw, fcb, (float*)d_out);
}

// Round 6
// 4818.933 us; speedup vs baseline: 1.1593x; 1.1593x over previous
//
#include <hip/hip_runtime.h>
#include <hip/hip_bf16.h>

// Shapes: B=128, L=512, D=13, H=128, G=4H=512.
typedef __attribute__((ext_vector_type(8))) short bf16x8;
typedef __attribute__((ext_vector_type(4))) float f32x4;
typedef __attribute__((ext_vector_type(2))) float f32x2;

__device__ __forceinline__ float bfbits(unsigned short u) {
  return __uint_as_float(((unsigned int)u) << 16);
}
__device__ __forceinline__ float sigf(float x) { return 1.f / (1.f + __expf(-x)); }
__device__ __forceinline__ float tanhf_(float x) {
  x = fminf(15.f, fmaxf(-15.f, x));
  float t = __expf(2.f * x);
  return (t - 1.f) / (t + 1.f);
}
// Gate-column permutation: pg = c*4 + g  <->  orig = g*128 + c.
__device__ __forceinline__ int permorig(int pg) {
  return (pg & 3) * 128 + (pg >> 2);
}

// ---------------------------------------------------------------------------
// Weight prep (all gate columns in PERMUTED order pg = c*4+g):
//   whht[lay][d][k][pg] fp32; wihbf (21|31|32) bf16 rows permuted; bsum permuted.
// ---------------------------------------------------------------------------
__global__ __launch_bounds__(256) void wconv(
    const float* whh0, const float* whh1, const float* whh2, const float* whh3, const float* whh4,
    const float* wi21, const float* wi31, const float* wi32,
    const float* bi0, const float* bh0, const float* bi1, const float* bh1,
    const float* bi2, const float* bh2, const float* bi3, const float* bh3,
    const float* bi4, const float* bh4,
    float* whht, __hip_bfloat16* wihbf, float* bsum)
{
  int tid = blockIdx.x * 256 + threadIdx.x;
  if (tid < 5 * 131072) {                       // whht: [5][2][128][512]
    int lay = tid / 131072, r = tid % 131072;
    const float* src = lay == 0 ? whh0 : lay == 1 ? whh1 : lay == 2 ? whh2 : lay == 3 ? whh3 : whh4;
    int d = r >> 16;
    int k = (r >> 9) & 127;
    int pg = r & 511;
    whht[tid] = src[((size_t)d * 512 + permorig(pg)) * 128 + k];
    return;
  }
  int t2 = tid - 5 * 131072;
  if (t2 < 1048576) {                           // wihbf: w21(K256) | w31(K512) | w32(K256)
    const float* src; int ci, K;
    if (t2 < 262144)      { src = wi21; ci = t2;          K = 256; }
    else if (t2 < 786432) { src = wi31; ci = t2 - 262144; K = 512; }
    else                  { src = wi32; ci = t2 - 786432; K = 256; }
    int d = ci / (512 * K), rr = ci % (512 * K);
    int pg = rr / K, k = rr % K;
    wihbf[t2] = __float2bfloat16(src[((size_t)d * 512 + permorig(pg)) * K + k]);
    return;
  }
  int t3 = t2 - 1048576;
  if (t3 < 5120) {                              // bsum: [5][2][512] permuted
    int lay = t3 >> 10, idx = t3 & 1023;
    int d = idx >> 9, pg = idx & 511;
    const float* bi = lay == 0 ? bi0 : lay == 1 ? bi1 : lay == 2 ? bi2 : lay == 3 ? bi3 : bi4;
    const float* bh = lay == 0 ? bh0 : lay == 1 ? bh1 : lay == 2 ? bh2 : lay == 3 ? bh3 : bh4;
    int o = d * 512 + permorig(pg);
    bsum[t3] = bi[o] + bh[o];
  }
}

// ---------------------------------------------------------------------------
// K=13 projection (layers 1, 22): xg[d][b][t][pg] bf16 (bias folded in).
// ---------------------------------------------------------------------------
__global__ __launch_bounds__(256) void proj13(
    const float* __restrict__ x, const float* __restrict__ wih,
    const float* __restrict__ bsum, __hip_bfloat16* __restrict__ xg)
{
  int tid = blockIdx.x * 256 + threadIdx.x;   // 2^26 threads
  int col = tid & 511;
  int bt  = (tid >> 9) & 65535;
  int d   = tid >> 25;
  const float* xp = x + (size_t)bt * 13;
  const float* wp = wih + ((size_t)d * 512 + permorig(col)) * 13;
  float acc = bsum[d * 512 + col];
#pragma unroll
  for (int k = 0; k < 13; ++k) acc += xp[k] * wp[k];
  xg[tid] = __float2bfloat16(acc);
}

// ---------------------------------------------------------------------------
// bf16 MFMA projection GEMM: out[d][row][col] = A[row,:K]·Bw[d][col,:K] + bs.
// (Bw rows and bs already permuted by wconv.)
// ---------------------------------------------------------------------------
__global__ __launch_bounds__(256) void projM(
    const __hip_bfloat16* __restrict__ A, int lda, int K,
    const __hip_bfloat16* __restrict__ Bw,
    const float* __restrict__ bsum,
    __hip_bfloat16* __restrict__ out)
{
  int d = blockIdx.z;
  const __hip_bfloat16* Bp = Bw + (size_t)d * 512 * K;
  const float* bs = bsum + d * 512;
  __hip_bfloat16* op = out + (size_t)d * 65536 * 512;
  int m0 = blockIdx.y * 128, n0 = blockIdx.x * 128;
  __shared__ __align__(16) __hip_bfloat16 As[128][32];
  __shared__ __align__(16) __hip_bfloat16 Bs[128][32];
  int tid = threadIdx.x, w = tid >> 6, l = tid & 63;
  int wm = (w >> 1) * 64, wn = (w & 1) * 64;
  f32x4 acc[4][4];
#pragma unroll
  for (int mi = 0; mi < 4; ++mi)
#pragma unroll
    for (int ni = 0; ni < 4; ++ni) acc[mi][ni] = (f32x4){0.f, 0.f, 0.f, 0.f};
  int srow = tid >> 2, sc = tid & 3;
  for (int k0 = 0; k0 < K; k0 += 32) {
#pragma unroll
    for (int p = 0; p < 2; ++p) {
      int row = p * 64 + srow;
      int slot = sc ^ (row & 3);
      uint4 va = *(const uint4*)(A + (size_t)(m0 + row) * lda + k0 + sc * 8);
      *(uint4*)(&As[row][slot * 8]) = va;
      uint4 vb = *(const uint4*)(Bp + (size_t)(n0 + row) * K + k0 + sc * 8);
      *(uint4*)(&Bs[row][slot * 8]) = vb;
    }
    __syncthreads();
    bf16x8 af[4], bfr[4];
#pragma unroll
    for (int mi = 0; mi < 4; ++mi) {
      int row = wm + mi * 16 + (l & 15);
      int slot = (l >> 4) ^ (row & 3);
      af[mi] = *(const bf16x8*)(&As[row][slot * 8]);
    }
#pragma unroll
    for (int ni = 0; ni < 4; ++ni) {
      int row = wn + ni * 16 + (l & 15);
      int slot = (l >> 4) ^ (row & 3);
      bfr[ni] = *(const bf16x8*)(&Bs[row][slot * 8]);
    }
#pragma unroll
    for (int mi = 0; mi < 4; ++mi)
#pragma unroll
      for (int ni = 0; ni < 4; ++ni)
        acc[mi][ni] = __builtin_amdgcn_mfma_f32_16x16x32_bf16(af[mi], bfr[ni], acc[mi][ni], 0, 0, 0);
    __syncthreads();
  }
#pragma unroll
  for (int ni = 0; ni < 4; ++ni) {
    int col = n0 + wn + ni * 16 + (l & 15);
    float bsv = bs[col];
#pragma unroll
    for (int mi = 0; mi < 4; ++mi) {
#pragma unroll
      for (int q = 0; q < 4; ++q) {
        int row = m0 + wm + mi * 16 + (l >> 4) * 4 + q;
        op[(size_t)row * 512 + col] = __float2bfloat16(acc[mi][ni][q] + bsv);
      }
    }
  }
}

// ---------------------------------------------------------------------------
// LSTM scan v5: block = (b, d), 1024 threads = (c in 0..127, q in 0..7),
// tid = c*8 + q. Thread computes ALL 4 gates of h-col c over k in [q*16,q*16+16):
// 32 packed-f32 FMAs on weights pinned once in registers; q-reduction via
// 3 shfl_xor stages; cell update redundant on all 8 q-lanes (no idle tail);
// h double-buffered in LDS; ONE barrier per step. y via LDS stage + 16-lane
// dwordx4 flush.
// ---------------------------------------------------------------------------
template<bool YOUT>
__global__ __launch_bounds__(1024, 4) void scan5(
    const __hip_bfloat16* __restrict__ xg,   // [2][B][512][512] permuted cols
    const float* __restrict__ whht,          // [2][128][512] permuted cols
    __hip_bfloat16* __restrict__ yout, int ycols, int ycoloff,
    float* __restrict__ y3out, int y3off)
{
  const int b = blockIdx.x, d = blockIdx.y;
  const int tid = threadIdx.x;
  const int c = tid >> 3, q = tid & 7;
  __shared__ __align__(16) float h_lds[2][128];
  __shared__ __align__(16) __hip_bfloat16 ystage[2][128];

  // weights: w2[g][p] = { W[d][q*16+2p][c*4+g], W[d][q*16+2p+1][c*4+g] }
  f32x2 w2[4][8];
  {
    const float* wp = whht + (size_t)d * 65536 + (size_t)(q * 16) * 512 + c * 4;
#pragma unroll
    for (int g = 0; g < 4; ++g)
#pragma unroll
      for (int p = 0; p < 8; ++p) {
        w2[g][p][0] = wp[(size_t)(2 * p) * 512 + g];
        w2[g][p][1] = wp[(size_t)(2 * p + 1) * 512 + g];
      }
  }
  // Pin once: forbids global-reload rematerialization (R2 failure mode).
  // Plain-C FMA consumers below leave the compiler free to read them from
  // wherever they live (no forced-VGPR copies — R4 failure mode).
#pragma unroll
  for (int g = 0; g < 4; ++g)
#pragma unroll
    for (int p = 0; p < 8; ++p) asm volatile("" : "+v"(w2[g][p]));

  const unsigned short* xgp = (const unsigned short*)xg + ((size_t)(d * 128 + b)) * 262144;

  if (tid < 128) h_lds[0][tid] = 0.f;
  float creg = 0.f, mreg = -1e30f;
  int cur = 0;
  int tt0 = d ? 511 : 0;
  ushort4 pf = *(const ushort4*)(xgp + (size_t)tt0 * 512 + c * 4);
  __syncthreads();

  for (int t = 0; t < 512; ++t) {
    int tn = (t + 1 < 512) ? t + 1 : 511;
    int ttn = d ? 511 - tn : tn;
    ushort4 pn = *(const ushort4*)(xgp + (size_t)ttn * 512 + c * 4);   // prefetch

    if (YOUT) {                     // flush h(t-1) from stage (coalesced 16B)
      if (t > 0 && tid < 16) {
        uint4 v = *(const uint4*)(&ystage[cur][tid * 8]);
        int tp = d ? 512 - t : t - 1;
        *(uint4*)(yout + ((size_t)b * 512 + tp) * ycols + ycoloff + d * 128 + tid * 8) = v;
      }
    }

    // h fragment: 16 floats = 4 x ds_read_b128
    const f32x4* h4p = (const f32x4*)&h_lds[cur][q * 16];
    f32x4 hA = h4p[0], hB = h4p[1], hC = h4p[2], hD = h4p[3];
    f32x2 hp[8];
    hp[0] = __builtin_shufflevector(hA, hA, 0, 1);
    hp[1] = __builtin_shufflevector(hA, hA, 2, 3);
    hp[2] = __builtin_shufflevector(hB, hB, 0, 1);
    hp[3] = __builtin_shufflevector(hB, hB, 2, 3);
    hp[4] = __builtin_shufflevector(hC, hC, 0, 1);
    hp[5] = __builtin_shufflevector(hC, hC, 2, 3);
    hp[6] = __builtin_shufflevector(hD, hD, 0, 1);
    hp[7] = __builtin_shufflevector(hD, hD, 2, 3);

    f32x2 a0 = {0.f, 0.f}, a1 = {0.f, 0.f}, a2 = {0.f, 0.f}, a3 = {0.f, 0.f};
#pragma unroll
    for (int p = 0; p < 8; ++p) {
      a0 = __builtin_elementwise_fma(w2[0][p], hp[p], a0);
      a1 = __builtin_elementwise_fma(w2[1][p], hp[p], a1);
      a2 = __builtin_elementwise_fma(w2[2][p], hp[p], a2);
      a3 = __builtin_elementwise_fma(w2[3][p], hp[p], a3);
    }
    float s0 = a0[0] + a0[1], s1 = a1[0] + a1[1], s2 = a2[0] + a2[1], s3 = a3[0] + a3[1];
    // reduce over q (3 butterfly stages, lanes differ only in low 3 bits)
    s0 += __shfl_xor(s0, 1); s1 += __shfl_xor(s1, 1); s2 += __shfl_xor(s2, 1); s3 += __shfl_xor(s3, 1);
    s0 += __shfl_xor(s0, 2); s1 += __shfl_xor(s1, 2); s2 += __shfl_xor(s2, 2); s3 += __shfl_xor(s3, 2);
    s0 += __shfl_xor(s0, 4); s1 += __shfl_xor(s1, 4); s2 += __shfl_xor(s2, 4); s3 += __shfl_xor(s3, 4);

    float gi = s0 + bfbits(pf.x);
    float gf = s1 + bfbits(pf.y);
    float gg = s2 + bfbits(pf.z);
    float go = s3 + bfbits(pf.w);
    creg = sigf(gf) * creg + sigf(gi) * tanhf_(gg);
    float h = sigf(go) * tanhf_(creg);
    if (q == 0) {
      h_lds[cur ^ 1][c] = h;
      if (YOUT) ystage[cur ^ 1][c] = __float2bfloat16(h);
    }
    if (!YOUT) mreg = fmaxf(mreg, h);
    __syncthreads();
    pf = pn; cur ^= 1;
  }
  if (YOUT) {
    if (tid < 16) {
      uint4 v = *(const uint4*)(&ystage[cur][tid * 8]);
      int tp = d ? 0 : 511;
      *(uint4*)(yout + ((size_t)b * 512 + tp) * ycols + ycoloff + d * 128 + tid * 8) = v;
    }
  } else if (q == 0) {
    y3out[(size_t)b * 512 + y3off + d * 128 + c] = mreg;   // keep d*128 (R3 bug!)
  }
}

// ---------------------------------------------------------------------------
// Head: y4 = selu(y3 @ l4w^T + l4b); out = sigmoid(y4 @ fcw^T + fcb).
// ---------------------------------------------------------------------------
__global__ __launch_bounds__(256) void head(
    const float* __restrict__ y3, const float* __restrict__ l4w,
    const float* __restrict__ l4b, const float* __restrict__ fcw,
    const float* __restrict__ fcb, float* __restrict__ outp)
{
  int b = blockIdx.x, t = threadIdx.x;
  __shared__ float row[512];
  __shared__ float y4[128];
  row[t] = y3[(size_t)b * 512 + t];
  row[t + 256] = y3[(size_t)b * 512 + t + 256];
  __syncthreads();
  if (t < 128) {
    float acc = l4b[t];
    const float* wr = l4w + (size_t)t * 512;
    for (int k = 0; k < 512; ++k) acc += row[k] * wr[k];
    const float scale = 1.0507009873554804934193349852946f;
    const float alpha = 1.6732632423543772848170429916717f;
    y4[t] = acc > 0.f ? scale * acc : scale * alpha * (__expf(acc) - 1.f);
  }
  __syncthreads();
  if (t < 2) {
    float acc = fcb[t];
    const float* wr = fcw + (size_t)t * 128;
    for (int k = 0; k < 128; ++k) acc += y4[k] * wr[k];
    outp[b * 2 + t] = 1.f / (1.f + __expf(-acc));
  }
}

extern "C" void kernel_launch(void* const* d_in, const int* in_sizes, int n_in,
                              void* d_out, int out_size, void* d_ws, size_t ws_size,
                              hipStream_t stream) {
  (void)in_sizes; (void)n_in; (void)out_size; (void)ws_size;
  const float* x     = (const float*)d_in[0];
  const float* Wih1  = (const float*)d_in[1];
  const float* Whh1  = (const float*)d_in[2];
  const float* bih1  = (const float*)d_in[3];
  const float* bhh1  = (const float*)d_in[4];
  const float* Wih21 = (const float*)d_in[5];
  const float* Whh21 = (const float*)d_in[6];
  const float* bih21 = (const float*)d_in[7];
  const float* bhh21 = (const float*)d_in[8];
  const float* Wih22 = (const float*)d_in[9];
  const float* Whh22 = (const float*)d_in[10];
  const float* bih22 = (const float*)d_in[11];
  const float* bhh22 = (const float*)d_in[12];
  const float* Wih31 = (const float*)d_in[13];
  const float* Whh31 = (const float*)d_in[14];
  const float* bih31 = (const float*)d_in[15];
  const float* bhh31 = (const float*)d_in[16];
  const float* Wih32 = (const float*)d_in[17];
  const float* Whh32 = (const float*)d_in[18];
  const float* bih32 = (const float*)d_in[19];
  const float* bhh32 = (const float*)d_in[20];
  const float* l4w   = (const float*)d_in[21];
  const float* l4b   = (const float*)d_in[22];
  const float* fcw   = (const float*)d_in[23];
  const float* fcb   = (const float*)d_in[24];

  char* ws = (char*)d_ws;
  __hip_bfloat16* xg    = (__hip_bfloat16*)(ws);               // 134217728 B
  __hip_bfloat16* y1    = (__hip_bfloat16*)(ws + 134217728);   // 33554432 B
  __hip_bfloat16* y2    = (__hip_bfloat16*)(ws + 167772160);   // 67108864 B
  float*          y3    = (float*)(ws + 234881024);            // 262144 B
  __hip_bfloat16* wihbf = (__hip_bfloat16*)(ws + 235143168);   // 2097152 B
  float*          bsum  = (float*)(ws + 237240320);            // 20480 B
  float*          whht  = (float*)(ws + 237260800);            // 2621440 B -> ~239.9 MB

  wconv<<<6677, 256, 0, stream>>>(Whh1, Whh21, Whh22, Whh31, Whh32,
                                  Wih21, Wih31, Wih32,
                                  bih1, bhh1, bih21, bhh21, bih22, bhh22,
                                  bih31, bhh31, bih32, bhh32,
                                  whht, wihbf, bsum);
  // layer 1: x -> y1
  proj13<<<262144, 256, 0, stream>>>(x, Wih1, bsum + 0 * 1024, xg);
  scan5<true><<<dim3(128, 2), 1024, 0, stream>>>(xg, whht + 0 * 131072, y1, 256, 0, nullptr, 0);
  // layer 22: x -> y2 cols 256..511
  proj13<<<262144, 256, 0, stream>>>(x, Wih22, bsum + 2 * 1024, xg);
  scan5<true><<<dim3(128, 2), 1024, 0, stream>>>(xg, whht + 2 * 131072, y2, 512, 256, nullptr, 0);
  // layer 21: y1 -> y2 cols 0..255
  projM<<<dim3(4, 512, 2), 256, 0, stream>>>(y1, 256, 256, wihbf + 0, bsum + 1 * 1024, xg);
  scan5<true><<<dim3(128, 2), 1024, 0, stream>>>(xg, whht + 1 * 131072, y2, 512, 0, nullptr, 0);
  // layer 31: y2 (K=512) -> y3 cols 0..255 (maxpool)
  projM<<<dim3(4, 512, 2), 256, 0, stream>>>(y2, 512, 512, wihbf + 262144, bsum + 3 * 1024, xg);
  scan5<false><<<dim3(128, 2), 1024, 0, stream>>>(xg, whht + 3 * 131072, nullptr, 0, 0, y3, 0);
  // layer 32: y21 (= y2 cols 0..255, K=256) -> y3 cols 256..511 (maxpool)
  projM<<<dim3(4, 512, 2), 256, 0, stream>>>(y2, 512, 256, wihbf + 786432, bsum + 4 * 1024, xg);
  scan5<false><<<dim3(128, 2), 1024, 0, stream>>>(xg, whht + 4 * 131072, nullptr, 0, 0, y3, 256);
  // head
  head<<<128, 256, 0, stream>>>(y3, l4w, l4b, fcw, fcb, (float*)d_out);
}

// Round 7
// 2830.712 us; speedup vs baseline: 1.9735x; 1.7024x over previous
//
#include <hip/hip_runtime.h>
#include <hip/hip_bf16.h>

// Shapes: B=128, L=512, D=13, H=128, G=4H=512.
typedef __attribute__((ext_vector_type(8))) short bf16x8;
typedef __attribute__((ext_vector_type(4))) float f32x4;
typedef __attribute__((ext_vector_type(2))) _Float16 f16x2;

__device__ __forceinline__ float bfbits(unsigned short u) {
  return __uint_as_float(((unsigned int)u) << 16);
}
__device__ __forceinline__ float sigf(float x) { return 1.f / (1.f + __expf(-x)); }
__device__ __forceinline__ float tanhf_(float x) {
  x = fminf(15.f, fmaxf(-15.f, x));
  float t = __expf(2.f * x);
  return (t - 1.f) / (t + 1.f);
}
#if __has_builtin(__builtin_amdgcn_fdot2)
__device__ __forceinline__ float FDOT2(f16x2 a, f16x2 b, float c) {
  return __builtin_amdgcn_fdot2(a, b, c, false);
}
#else
__device__ __forceinline__ float FDOT2(f16x2 a, f16x2 b, float c) {
  return c + (float)a.x * (float)b.x + (float)a.y * (float)b.y;
}
#endif
__device__ __forceinline__ f16x2 h2bc(unsigned int u) {
  return __builtin_bit_cast(f16x2, u);
}

// ---------------------------------------------------------------------------
// Weight prep (original gate order, R4-proven):
//   whht[lay][d][k][j] fp32 (transposed); wihbf (21|31|32) bf16; bsum=bih+bhh.
// ---------------------------------------------------------------------------
__global__ __launch_bounds__(256) void wconv(
    const float* whh0, const float* whh1, const float* whh2, const float* whh3, const float* whh4,
    const float* wi21, const float* wi31, const float* wi32,
    const float* bi0, const float* bh0, const float* bi1, const float* bh1,
    const float* bi2, const float* bh2, const float* bi3, const float* bh3,
    const float* bi4, const float* bh4,
    float* whht, __hip_bfloat16* wihbf, float* bsum)
{
  int tid = blockIdx.x * 256 + threadIdx.x;
  if (tid < 5 * 131072) {                       // whht: [5][2][128][512]
    int lay = tid / 131072, r = tid % 131072;
    const float* src = lay == 0 ? whh0 : lay == 1 ? whh1 : lay == 2 ? whh2 : lay == 3 ? whh3 : whh4;
    int d = r >> 16;
    int k = (r >> 9) & 127;
    int j = r & 511;
    whht[tid] = src[((size_t)d * 512 + j) * 128 + k];   // Whh[d][j][k]
    return;
  }
  int t2 = tid - 5 * 131072;
  if (t2 < 1048576) {                           // wihbf: w21 | w31 | w32 (bf16)
    const float* src; int idx;
    if (t2 < 262144)      { src = wi21; idx = t2; }
    else if (t2 < 786432) { src = wi31; idx = t2 - 262144; }
    else                  { src = wi32; idx = t2 - 786432; }
    wihbf[t2] = __float2bfloat16(src[idx]);
    return;
  }
  int t3 = t2 - 1048576;
  if (t3 < 5120) {                              // bsum: [5][2][512]
    int lay = t3 >> 10, idx = t3 & 1023;
    const float* bi = lay == 0 ? bi0 : lay == 1 ? bi1 : lay == 2 ? bi2 : lay == 3 ? bi3 : bi4;
    const float* bh = lay == 0 ? bh0 : lay == 1 ? bh1 : lay == 2 ? bh2 : lay == 3 ? bh3 : bh4;
    bsum[t3] = bi[idx] + bh[idx];
  }
}

// ---------------------------------------------------------------------------
// K=13 projection (layers 1, 22): xg[d][b][t][512] bf16, bias folded in.
// ---------------------------------------------------------------------------
__global__ __launch_bounds__(256) void proj13(
    const float* __restrict__ x, const float* __restrict__ wih,
    const float* __restrict__ bsum, __hip_bfloat16* __restrict__ xg)
{
  int tid = blockIdx.x * 256 + threadIdx.x;   // 2^26 threads
  int col = tid & 511;
  int bt  = (tid >> 9) & 65535;
  int d   = tid >> 25;
  const float* xp = x + (size_t)bt * 13;
  const float* wp = wih + ((size_t)d * 512 + col) * 13;
  float acc = bsum[d * 512 + col];
#pragma unroll
  for (int k = 0; k < 13; ++k) acc += xp[k] * wp[k];
  xg[tid] = __float2bfloat16(acc);
}

// ---------------------------------------------------------------------------
// bf16 MFMA projection GEMM (R4-proven): out[d][row][col], row = b*512+t.
// ---------------------------------------------------------------------------
__global__ __launch_bounds__(256) void projM(
    const __hip_bfloat16* __restrict__ A, int lda, int K,
    const __hip_bfloat16* __restrict__ Bw,
    const float* __restrict__ bsum,
    __hip_bfloat16* __restrict__ out)
{
  int d = blockIdx.z;
  const __hip_bfloat16* Bp = Bw + (size_t)d * 512 * K;
  const float* bs = bsum + d * 512;
  __hip_bfloat16* op = out + (size_t)d * 65536 * 512;
  int m0 = blockIdx.y * 128, n0 = blockIdx.x * 128;
  __shared__ __align__(16) __hip_bfloat16 As[128][32];
  __shared__ __align__(16) __hip_bfloat16 Bs[128][32];
  int tid = threadIdx.x, w = tid >> 6, l = tid & 63;
  int wm = (w >> 1) * 64, wn = (w & 1) * 64;
  f32x4 acc[4][4];
#pragma unroll
  for (int mi = 0; mi < 4; ++mi)
#pragma unroll
    for (int ni = 0; ni < 4; ++ni) acc[mi][ni] = (f32x4){0.f, 0.f, 0.f, 0.f};
  int srow = tid >> 2, sc = tid & 3;
  for (int k0 = 0; k0 < K; k0 += 32) {
#pragma unroll
    for (int p = 0; p < 2; ++p) {
      int row = p * 64 + srow;
      int slot = sc ^ (row & 3);
      uint4 va = *(const uint4*)(A + (size_t)(m0 + row) * lda + k0 + sc * 8);
      *(uint4*)(&As[row][slot * 8]) = va;
      uint4 vb = *(const uint4*)(Bp + (size_t)(n0 + row) * K + k0 + sc * 8);
      *(uint4*)(&Bs[row][slot * 8]) = vb;
    }
    __syncthreads();
    bf16x8 af[4], bfr[4];
#pragma unroll
    for (int mi = 0; mi < 4; ++mi) {
      int row = wm + mi * 16 + (l & 15);
      int slot = (l >> 4) ^ (row & 3);
      af[mi] = *(const bf16x8*)(&As[row][slot * 8]);
    }
#pragma unroll
    for (int ni = 0; ni < 4; ++ni) {
      int row = wn + ni * 16 + (l & 15);
      int slot = (l >> 4) ^ (row & 3);
      bfr[ni] = *(const bf16x8*)(&Bs[row][slot * 8]);
    }
#pragma unroll
    for (int mi = 0; mi < 4; ++mi)
#pragma unroll
      for (int ni = 0; ni < 4; ++ni)
        acc[mi][ni] = __builtin_amdgcn_mfma_f32_16x16x32_bf16(af[mi], bfr[ni], acc[mi][ni], 0, 0, 0);
    __syncthreads();
  }
#pragma unroll
  for (int ni = 0; ni < 4; ++ni) {
    int col = n0 + wn + ni * 16 + (l & 15);
    float bsv = bs[col];
#pragma unroll
    for (int mi = 0; mi < 4; ++mi) {
#pragma unroll
      for (int q = 0; q < 4; ++q) {
        int row = m0 + wm + mi * 16 + (l >> 4) * 4 + q;
        op[(size_t)row * 512 + col] = __float2bfloat16(acc[mi][ni][q] + bsv);
      }
    }
  }
}

// ---------------------------------------------------------------------------
// LSTM scan v6: scan3 structure + fp16 weights consumed by v_dot2_f32_f16.
// block = (b, d, z-layer), 1024 threads = (kq in 0..3, gate-pair j2).
// Thread: gates j2 and j2+256 over k in [kq*32, kq*32+32): 32 dot2 instrs on
// 32 packed-fp16 weight dwords. h kept packed-fp16 in LDS (wave-uniform
// broadcast reads). Reduction via p_lds[4][512]; cell on threads 0..127,
// exact fp32 c. <=64 regs/thread -> __launch_bounds__(1024,8) -> 2 blocks/CU,
// enabling fused independent-layer dispatches (gridDim.z=2).
// ---------------------------------------------------------------------------
struct ScanP {
  const __hip_bfloat16* xg;   // [2][B][512][512] this layer
  const float* whht;          // [2][128][512] this layer
  __hip_bfloat16* yout; int ycols; int ycoloff;
  float* y3out; int y3off;    // maxpool mode when yout == nullptr
};

__global__ __launch_bounds__(1024, 8) void scan6(ScanP pa, ScanP pb)
{
  ScanP P = blockIdx.z ? pb : pa;
  const int b = blockIdx.x, d = blockIdx.y;
  const int tid = threadIdx.x;
  const int kq = tid >> 8, j2 = tid & 255;     // kq is wave-uniform
  __shared__ unsigned int hpk[2][64];          // h as packed fp16 pairs
  __shared__ float p_lds[4][512];

  // weights -> packed fp16 pairs: w16[g2*16+m] = {W[k],W[k+1]} col j2+256*g2
  f16x2 w16[32];
  {
    const float* wp = P.whht + (size_t)d * 65536;
#pragma unroll
    for (int g2 = 0; g2 < 2; ++g2)
#pragma unroll
      for (int m = 0; m < 16; ++m) {
        int k = kq * 32 + 2 * m;
        int col = j2 + g2 * 256;
        f16x2 t;
        t.x = (_Float16)wp[(size_t)k * 512 + col];
        t.y = (_Float16)wp[(size_t)(k + 1) * 512 + col];
        w16[g2 * 16 + m] = t;
      }
  }
#pragma unroll
  for (int i = 0; i < 32; ++i) asm volatile("" : "+v"(w16[i]));

  const unsigned short* xgp = (const unsigned short*)P.xg + ((size_t)(d * 128 + b)) * 262144;

  if (tid < 64) hpk[0][tid] = 0u;
  float creg = 0.f, mreg = -1e30f;
  int cur = 0;
  int tt0 = d ? 511 : 0;
  unsigned short pfa = 0, pfb = 0;
  if (kq == 0) {
    pfa = xgp[(size_t)tt0 * 512 + j2];
    pfb = xgp[(size_t)tt0 * 512 + j2 + 256];
  }
  __syncthreads();

  for (int t = 0; t < 512; ++t) {
    int tt = d ? 511 - t : t;
    int tn = (t + 1 < 512) ? t + 1 : 511;
    int ttn = d ? 511 - tn : tn;
    unsigned short pna = 0, pnb = 0;
    if (kq == 0) {                               // prefetch next xg
      pna = xgp[(size_t)ttn * 512 + j2];
      pnb = xgp[(size_t)ttn * 512 + j2 + 256];
    }

    // h slice (wave-uniform address -> LDS broadcast, conflict-free)
    const uint4* hb4 = (const uint4*)&hpk[cur][kq * 16];
    uint4 hA = hb4[0], hB = hb4[1];
    float a00 = 0.f, a01 = 0.f, a10 = 0.f, a11 = 0.f;
    unsigned int u0[8] = {hA.x, hA.y, hA.z, hA.w, hB.x, hB.y, hB.z, hB.w};
#pragma unroll
    for (int m = 0; m < 8; m += 2) {
      f16x2 h0 = h2bc(u0[m]), h1 = h2bc(u0[m + 1]);
      a00 = FDOT2(w16[m], h0, a00);
      a01 = FDOT2(w16[m + 1], h1, a01);
      a10 = FDOT2(w16[16 + m], h0, a10);
      a11 = FDOT2(w16[16 + m + 1], h1, a11);
    }
    uint4 hC = hb4[2], hD = hb4[3];
    unsigned int u1[8] = {hC.x, hC.y, hC.z, hC.w, hD.x, hD.y, hD.z, hD.w};
#pragma unroll
    for (int m = 0; m < 8; m += 2) {
      f16x2 h0 = h2bc(u1[m]), h1 = h2bc(u1[m + 1]);
      a00 = FDOT2(w16[8 + m], h0, a00);
      a01 = FDOT2(w16[8 + m + 1], h1, a01);
      a10 = FDOT2(w16[24 + m], h0, a10);
      a11 = FDOT2(w16[24 + m + 1], h1, a11);
    }

    float s0 = a00 + a01, s1 = a10 + a11;
    if (kq == 0) { s0 += bfbits(pfa); s1 += bfbits(pfb); }
    p_lds[kq][j2] = s0;
    p_lds[kq][j2 + 256] = s1;
    __syncthreads();
    if (tid < 128) {
      float gi = p_lds[0][tid]       + p_lds[1][tid]       + p_lds[2][tid]       + p_lds[3][tid];
      float gf = p_lds[0][tid + 128] + p_lds[1][tid + 128] + p_lds[2][tid + 128] + p_lds[3][tid + 128];
      float gg = p_lds[0][tid + 256] + p_lds[1][tid + 256] + p_lds[2][tid + 256] + p_lds[3][tid + 256];
      float go = p_lds[0][tid + 384] + p_lds[1][tid + 384] + p_lds[2][tid + 384] + p_lds[3][tid + 384];
      creg = sigf(gf) * creg + sigf(gi) * tanhf_(gg);
      float h = sigf(go) * tanhf_(creg);
      _Float16 hf = (_Float16)h;
      ((unsigned short*)&hpk[cur ^ 1][0])[tid] = __builtin_bit_cast(unsigned short, hf);
      if (P.yout)
        P.yout[((size_t)b * 512 + tt) * P.ycols + P.ycoloff + d * 128 + tid] = __float2bfloat16(h);
      else
        mreg = fmaxf(mreg, h);
    }
    __syncthreads();
    pfa = pna; pfb = pnb; cur ^= 1;
  }
  // d*128 offset REQUIRED (R3 lesson)
  if (!P.yout && tid < 128)
    P.y3out[(size_t)b * 512 + P.y3off + d * 128 + tid] = mreg;
}

// ---------------------------------------------------------------------------
// Head: y4 = selu(y3 @ l4w^T + l4b); out = sigmoid(y4 @ fcw^T + fcb).
// ---------------------------------------------------------------------------
__global__ __launch_bounds__(256) void head(
    const float* __restrict__ y3, const float* __restrict__ l4w,
    const float* __restrict__ l4b, const float* __restrict__ fcw,
    const float* __restrict__ fcb, float* __restrict__ outp)
{
  int b = blockIdx.x, t = threadIdx.x;
  __shared__ float row[512];
  __shared__ float y4[128];
  row[t] = y3[(size_t)b * 512 + t];
  row[t + 256] = y3[(size_t)b * 512 + t + 256];
  __syncthreads();
  if (t < 128) {
    float acc = l4b[t];
    const float* wr = l4w + (size_t)t * 512;
    for (int k = 0; k < 512; ++k) acc += row[k] * wr[k];
    const float scale = 1.0507009873554804934193349852946f;
    const float alpha = 1.6732632423543772848170429916717f;
    y4[t] = acc > 0.f ? scale * acc : scale * alpha * (__expf(acc) - 1.f);
  }
  __syncthreads();
  if (t < 2) {
    float acc = fcb[t];
    const float* wr = fcw + (size_t)t * 128;
    for (int k = 0; k < 128; ++k) acc += y4[k] * wr[k];
    outp[b * 2 + t] = 1.f / (1.f + __expf(-acc));
  }
}

extern "C" void kernel_launch(void* const* d_in, const int* in_sizes, int n_in,
                              void* d_out, int out_size, void* d_ws, size_t ws_size,
                              hipStream_t stream) {
  (void)in_sizes; (void)n_in; (void)out_size;
  const float* x     = (const float*)d_in[0];
  const float* Wih1  = (const float*)d_in[1];
  const float* Whh1  = (const float*)d_in[2];
  const float* bih1  = (const float*)d_in[3];
  const float* bhh1  = (const float*)d_in[4];
  const float* Wih21 = (const float*)d_in[5];
  const float* Whh21 = (const float*)d_in[6];
  const float* bih21 = (const float*)d_in[7];
  const float* bhh21 = (const float*)d_in[8];
  const float* Wih22 = (const float*)d_in[9];
  const float* Whh22 = (const float*)d_in[10];
  const float* bih22 = (const float*)d_in[11];
  const float* bhh22 = (const float*)d_in[12];
  const float* Wih31 = (const float*)d_in[13];
  const float* Whh31 = (const float*)d_in[14];
  const float* bih31 = (const float*)d_in[15];
  const float* bhh31 = (const float*)d_in[16];
  const float* Wih32 = (const float*)d_in[17];
  const float* Whh32 = (const float*)d_in[18];
  const float* bih32 = (const float*)d_in[19];
  const float* bhh32 = (const float*)d_in[20];
  const float* l4w   = (const float*)d_in[21];
  const float* l4b   = (const float*)d_in[22];
  const float* fcw   = (const float*)d_in[23];
  const float* fcb   = (const float*)d_in[24];

  char* ws = (char*)d_ws;
  const size_t NEED_FUSED = 374099968ull;
  bool fused = (ws_size >= NEED_FUSED);

  __hip_bfloat16 *xgA, *xgB, *y1, *y2;
  float *y3, *bsum, *whht;
  __hip_bfloat16 *wihbf;
  if (fused) {
    xgA   = (__hip_bfloat16*)(ws);
    xgB   = (__hip_bfloat16*)(ws + 134217728);
    y1    = (__hip_bfloat16*)(ws + 268435456);
    y2    = (__hip_bfloat16*)(ws + 301989888);
    y3    = (float*)(ws + 369098752);
    wihbf = (__hip_bfloat16*)(ws + 369360896);
    bsum  = (float*)(ws + 371458048);
    whht  = (float*)(ws + 371478528);
  } else {
    xgA   = (__hip_bfloat16*)(ws);
    xgB   = xgA;                                 // sequential: single xg
    y1    = (__hip_bfloat16*)(ws + 134217728);
    y2    = (__hip_bfloat16*)(ws + 167772160);
    y3    = (float*)(ws + 234881024);
    wihbf = (__hip_bfloat16*)(ws + 235143168);
    bsum  = (float*)(ws + 237240320);
    whht  = (float*)(ws + 237260800);
  }

  wconv<<<6676, 256, 0, stream>>>(Whh1, Whh21, Whh22, Whh31, Whh32,
                                  Wih21, Wih31, Wih32,
                                  bih1, bhh1, bih21, bhh21, bih22, bhh22,
                                  bih31, bhh31, bih32, bhh32,
                                  whht, wihbf, bsum);

  ScanP P1  = {xgA, whht + 0 * 131072, y1, 256, 0,   nullptr, 0};
  ScanP P22 = {xgB, whht + 2 * 131072, y2, 512, 256, nullptr, 0};
  ScanP P21 = {xgA, whht + 1 * 131072, y2, 512, 0,   nullptr, 0};
  ScanP P31 = {xgA, whht + 3 * 131072, nullptr, 0, 0, y3, 0};
  ScanP P32 = {xgB, whht + 4 * 131072, nullptr, 0, 0, y3, 256};

  if (fused) {
    proj13<<<262144, 256, 0, stream>>>(x, Wih1,  bsum + 0 * 1024, xgA);
    proj13<<<262144, 256, 0, stream>>>(x, Wih22, bsum + 2 * 1024, xgB);
    scan6<<<dim3(128, 2, 2), 1024, 0, stream>>>(P1, P22);        // layers 1 || 22
    projM<<<dim3(4, 512, 2), 256, 0, stream>>>(y1, 256, 256, wihbf + 0,      bsum + 1 * 1024, xgA);
    scan6<<<dim3(128, 2, 1), 1024, 0, stream>>>(P21, P21);       // layer 21
    projM<<<dim3(4, 512, 2), 256, 0, stream>>>(y2, 512, 512, wihbf + 262144, bsum + 3 * 1024, xgA);
    projM<<<dim3(4, 512, 2), 256, 0, stream>>>(y2, 512, 256, wihbf + 786432, bsum + 4 * 1024, xgB);
    scan6<<<dim3(128, 2, 2), 1024, 0, stream>>>(P31, P32);       // layers 31 || 32
  } else {
    proj13<<<262144, 256, 0, stream>>>(x, Wih1, bsum + 0 * 1024, xgA);
    scan6<<<dim3(128, 2, 1), 1024, 0, stream>>>(P1, P1);
    proj13<<<262144, 256, 0, stream>>>(x, Wih22, bsum + 2 * 1024, xgA);
    scan6<<<dim3(128, 2, 1), 1024, 0, stream>>>(P22, P22);
    projM<<<dim3(4, 512, 2), 256, 0, stream>>>(y1, 256, 256, wihbf + 0,      bsum + 1 * 1024, xgA);
    scan6<<<dim3(128, 2, 1), 1024, 0, stream>>>(P21, P21);
    projM<<<dim3(4, 512, 2), 256, 0, stream>>>(y2, 512, 512, wihbf + 262144, bsum + 3 * 1024, xgA);
    scan6<<<dim3(128, 2, 1), 1024, 0, stream>>>(P31, P31);
    projM<<<dim3(4, 512, 2), 256, 0, stream>>>(y2, 512, 256, wihbf + 786432, bsum + 4 * 1024, xgA);
    scan6<<<dim3(128, 2, 1), 1024, 0, stream>>>(P32, P32);
  }
  head<<<128, 256, 0, stream>>>(y3, l4w, l4b, fcw, fcb, (float*)d_out);
}

// Round 8
// 2114.911 us; speedup vs baseline: 2.6415x; 1.3385x over previous
//
#include <hip/hip_runtime.h>
#include <hip/hip_bf16.h>

// Shapes: B=128, L=512, D=13, H=128, G=4H=512.
typedef __attribute__((ext_vector_type(8))) short bf16x8;
typedef __attribute__((ext_vector_type(4))) float f32x4;
typedef __attribute__((ext_vector_type(2))) _Float16 f16x2;

__device__ __forceinline__ float bfbits(unsigned short u) {
  return __uint_as_float(((unsigned int)u) << 16);
}
__device__ __forceinline__ float sigf(float x) { return 1.f / (1.f + __expf(-x)); }
__device__ __forceinline__ float tanhf_(float x) {
  x = fminf(15.f, fmaxf(-15.f, x));
  float t = __expf(2.f * x);
  return (t - 1.f) / (t + 1.f);
}
#if __has_builtin(__builtin_amdgcn_fdot2)
__device__ __forceinline__ float FDOT2(f16x2 a, f16x2 b, float c) {
  return __builtin_amdgcn_fdot2(a, b, c, false);
}
#else
__device__ __forceinline__ float FDOT2(f16x2 a, f16x2 b, float c) {
  return c + (float)a.x * (float)b.x + (float)a.y * (float)b.y;
}
#endif
__device__ __forceinline__ f16x2 h2bc(unsigned int u) {
  return __builtin_bit_cast(f16x2, u);
}
__device__ __forceinline__ unsigned packh(float a, float b) {
  _Float16 ha = (_Float16)a, hb = (_Float16)b;
  return (unsigned)__builtin_bit_cast(unsigned short, ha) |
         ((unsigned)__builtin_bit_cast(unsigned short, hb) << 16);
}

// ---------------------------------------------------------------------------
// Weight prep: whht[lay][d][k][j] fp32 transposed; wihbf (21|31|32) bf16;
// bsum = bih + bhh.
// ---------------------------------------------------------------------------
__global__ __launch_bounds__(256) void wconv(
    const float* whh0, const float* whh1, const float* whh2, const float* whh3, const float* whh4,
    const float* wi21, const float* wi31, const float* wi32,
    const float* bi0, const float* bh0, const float* bi1, const float* bh1,
    const float* bi2, const float* bh2, const float* bi3, const float* bh3,
    const float* bi4, const float* bh4,
    float* whht, __hip_bfloat16* wihbf, float* bsum)
{
  int tid = blockIdx.x * 256 + threadIdx.x;
  if (tid < 5 * 131072) {                       // whht: [5][2][128][512]
    int lay = tid / 131072, r = tid % 131072;
    const float* src = lay == 0 ? whh0 : lay == 1 ? whh1 : lay == 2 ? whh2 : lay == 3 ? whh3 : whh4;
    int d = r >> 16;
    int k = (r >> 9) & 127;
    int j = r & 511;
    whht[tid] = src[((size_t)d * 512 + j) * 128 + k];
    return;
  }
  int t2 = tid - 5 * 131072;
  if (t2 < 1048576) {                           // wihbf: w21 | w31 | w32 (bf16)
    const float* src; int idx;
    if (t2 < 262144)      { src = wi21; idx = t2; }
    else if (t2 < 786432) { src = wi31; idx = t2 - 262144; }
    else                  { src = wi32; idx = t2 - 786432; }
    wihbf[t2] = __float2bfloat16(src[idx]);
    return;
  }
  int t3 = t2 - 1048576;
  if (t3 < 5120) {                              // bsum: [5][2][512]
    int lay = t3 >> 10, idx = t3 & 1023;
    const float* bi = lay == 0 ? bi0 : lay == 1 ? bi1 : lay == 2 ? bi2 : lay == 3 ? bi3 : bi4;
    const float* bh = lay == 0 ? bh0 : lay == 1 ? bh1 : lay == 2 ? bh2 : lay == 3 ? bh3 : bh4;
    bsum[t3] = bi[idx] + bh[idx];
  }
}

// ---------------------------------------------------------------------------
// bf16 MFMA projection GEMM (unchanged, proven).
// ---------------------------------------------------------------------------
__global__ __launch_bounds__(256) void projM(
    const __hip_bfloat16* __restrict__ A, int lda, int K,
    const __hip_bfloat16* __restrict__ Bw,
    const float* __restrict__ bsum,
    __hip_bfloat16* __restrict__ out)
{
  int d = blockIdx.z;
  const __hip_bfloat16* Bp = Bw + (size_t)d * 512 * K;
  const float* bs = bsum + d * 512;
  __hip_bfloat16* op = out + (size_t)d * 65536 * 512;
  int m0 = blockIdx.y * 128, n0 = blockIdx.x * 128;
  __shared__ __align__(16) __hip_bfloat16 As[128][32];
  __shared__ __align__(16) __hip_bfloat16 Bs[128][32];
  int tid = threadIdx.x, w = tid >> 6, l = tid & 63;
  int wm = (w >> 1) * 64, wn = (w & 1) * 64;
  f32x4 acc[4][4];
#pragma unroll
  for (int mi = 0; mi < 4; ++mi)
#pragma unroll
    for (int ni = 0; ni < 4; ++ni) acc[mi][ni] = (f32x4){0.f, 0.f, 0.f, 0.f};
  int srow = tid >> 2, sc = tid & 3;
  for (int k0 = 0; k0 < K; k0 += 32) {
#pragma unroll
    for (int p = 0; p < 2; ++p) {
      int row = p * 64 + srow;
      int slot = sc ^ (row & 3);
      uint4 va = *(const uint4*)(A + (size_t)(m0 + row) * lda + k0 + sc * 8);
      *(uint4*)(&As[row][slot * 8]) = va;
      uint4 vb = *(const uint4*)(Bp + (size_t)(n0 + row) * K + k0 + sc * 8);
      *(uint4*)(&Bs[row][slot * 8]) = vb;
    }
    __syncthreads();
    bf16x8 af[4], bfr[4];
#pragma unroll
    for (int mi = 0; mi < 4; ++mi) {
      int row = wm + mi * 16 + (l & 15);
      int slot = (l >> 4) ^ (row & 3);
      af[mi] = *(const bf16x8*)(&As[row][slot * 8]);
    }
#pragma unroll
    for (int ni = 0; ni < 4; ++ni) {
      int row = wn + ni * 16 + (l & 15);
      int slot = (l >> 4) ^ (row & 3);
      bfr[ni] = *(const bf16x8*)(&Bs[row][slot * 8]);
    }
#pragma unroll
    for (int mi = 0; mi < 4; ++mi)
#pragma unroll
      for (int ni = 0; ni < 4; ++ni)
        acc[mi][ni] = __builtin_amdgcn_mfma_f32_16x16x32_bf16(af[mi], bfr[ni], acc[mi][ni], 0, 0, 0);
    __syncthreads();
  }
#pragma unroll
  for (int ni = 0; ni < 4; ++ni) {
    int col = n0 + wn + ni * 16 + (l & 15);
    float bsv = bs[col];
#pragma unroll
    for (int mi = 0; mi < 4; ++mi) {
#pragma unroll
      for (int q = 0; q < 4; ++q) {
        int row = m0 + wm + mi * 16 + (l >> 4) * 4 + q;
        op[(size_t)row * 512 + col] = __float2bfloat16(acc[mi][ni][q] + bsv);
      }
    }
  }
}

// ---------------------------------------------------------------------------
// LSTM scan v7: dual-layer software-pipelined scan.
// block=(b,d), 1024 threads=(kq,j2). Two independent layers A,B per block:
//  phase-a: dots_A(t) [all waves] || cell_B(t-1) [threads 128..255]; barrier
//  phase-b: dots_B(t) [all waves] || cell_A(t)   [threads 0..127];   barrier
// Each phase has full-width dot work hiding the other layer's serial cell
// chain. FUSE: D=13 input projection in-dot (x padded to 16 dims, packed
// f16 in LDS; bias via x[15]=1 weight trick) -> no xg buffer at all.
// ---------------------------------------------------------------------------
struct ScanP {
  const __hip_bfloat16* xg;   // non-FUSE: [2][B][512][512]
  const float* wihx;          // FUSE: original Wih [2][512][13]
  const float* bs;            // FUSE: bsum for this layer [2][512]
  const float* whht;          // [2][128][512]
  __hip_bfloat16* yout; int ycols; int ycoloff;
  float* y3out; int y3off;    // maxpool mode when yout == nullptr
};

#define DOT32(W, HL, curx, S0, S1) { \
  const uint4* hb4_ = (const uint4*)&HL[curx][kq * 16]; \
  uint4 hA_ = hb4_[0], hB_ = hb4_[1]; \
  float a00_ = 0.f, a01_ = 0.f, a10_ = 0.f, a11_ = 0.f; \
  unsigned int u0_[8] = {hA_.x, hA_.y, hA_.z, hA_.w, hB_.x, hB_.y, hB_.z, hB_.w}; \
  _Pragma("unroll") \
  for (int m = 0; m < 8; m += 2) { \
    f16x2 h0_ = h2bc(u0_[m]), h1_ = h2bc(u0_[m + 1]); \
    a00_ = FDOT2(W[m], h0_, a00_);           a01_ = FDOT2(W[m + 1], h1_, a01_); \
    a10_ = FDOT2(W[16 + m], h0_, a10_);      a11_ = FDOT2(W[16 + m + 1], h1_, a11_); } \
  uint4 hC_ = hb4_[2], hD_ = hb4_[3]; \
  unsigned int u1_[8] = {hC_.x, hC_.y, hC_.z, hC_.w, hD_.x, hD_.y, hD_.z, hD_.w}; \
  _Pragma("unroll") \
  for (int m = 0; m < 8; m += 2) { \
    f16x2 h0_ = h2bc(u1_[m]), h1_ = h2bc(u1_[m + 1]); \
    a00_ = FDOT2(W[8 + m], h0_, a00_);       a01_ = FDOT2(W[8 + m + 1], h1_, a01_); \
    a10_ = FDOT2(W[24 + m], h0_, a10_);      a11_ = FDOT2(W[24 + m + 1], h1_, a11_); } \
  S0 = a00_ + a01_; S1 = a10_ + a11_; }

#define CELLPHASE(P, CT, PL, HL, CURX, TROW) { \
  int ct_ = (CT); \
  float gi = PL[0][ct_] + PL[1][ct_] + PL[2][ct_] + PL[3][ct_]; \
  float gf = PL[0][ct_ + 128] + PL[1][ct_ + 128] + PL[2][ct_ + 128] + PL[3][ct_ + 128]; \
  float gg = PL[0][ct_ + 256] + PL[1][ct_ + 256] + PL[2][ct_ + 256] + PL[3][ct_ + 256]; \
  float go = PL[0][ct_ + 384] + PL[1][ct_ + 384] + PL[2][ct_ + 384] + PL[3][ct_ + 384]; \
  creg = sigf(gf) * creg + sigf(gi) * tanhf_(gg); \
  float h_ = sigf(go) * tanhf_(creg); \
  _Float16 hf_ = (_Float16)h_; \
  ((unsigned short*)&HL[CURX][0])[ct_] = __builtin_bit_cast(unsigned short, hf_); \
  if (P.yout) P.yout[((size_t)b * 512 + (TROW)) * P.ycols + P.ycoloff + d * 128 + ct_] = __float2bfloat16(h_); \
  else mreg = fmaxf(mreg, h_); }

template<bool DUALB, bool FUSE>
__global__ __launch_bounds__(1024, 4) void scan7(ScanP pa, ScanP pb, const float* xin)
{
  const int b = blockIdx.x, d = blockIdx.y;
  const int tid = threadIdx.x;
  const int kq = tid >> 8, j2 = tid & 255;
  __shared__ unsigned int hA[2][64];
  __shared__ unsigned int hB[DUALB ? 2 : 1][64];
  __shared__ float pA[4][512];
  __shared__ float pB[DUALB ? 4 : 1][512];
  __shared__ unsigned int x_lds[FUSE ? 4096 : 4];   // [t][8] packed f16 pairs (16 dims)

  // --- recurrent weights (packed f16 pairs; AGPR-friendly consumers) -------
  f16x2 w16A[32], w16B[DUALB ? 32 : 1];
  {
    const float* wp = pa.whht + (size_t)d * 65536;
#pragma unroll
    for (int g2 = 0; g2 < 2; ++g2)
#pragma unroll
      for (int m = 0; m < 16; ++m) {
        int k = kq * 32 + 2 * m;
        int col = j2 + g2 * 256;
        f16x2 t;
        t.x = (_Float16)wp[(size_t)k * 512 + col];
        t.y = (_Float16)wp[(size_t)(k + 1) * 512 + col];
        w16A[g2 * 16 + m] = t;
      }
  }
  if (DUALB) {
    const float* wp = pb.whht + (size_t)d * 65536;
#pragma unroll
    for (int g2 = 0; g2 < 2; ++g2)
#pragma unroll
      for (int m = 0; m < 16; ++m) {
        int k = kq * 32 + 2 * m;
        int col = j2 + g2 * 256;
        f16x2 t;
        t.x = (_Float16)wp[(size_t)k * 512 + col];
        t.y = (_Float16)wp[(size_t)(k + 1) * 512 + col];
        w16B[g2 * 16 + m] = t;
      }
  }
#pragma unroll
  for (int i = 0; i < 32; ++i) asm volatile("" : "+v"(w16A[i]));
  if (DUALB) {
#pragma unroll
    for (int i = 0; i < 32; ++i) asm volatile("" : "+v"(w16B[i]));
  }

  // --- FUSE: x-projection weights, dims padded to 16; dim15 = bias, x15=1 --
  f16x2 wxA[4], wxB[4];
  if (FUSE) {
    int kd = kq * 4;
#pragma unroll
    for (int g2 = 0; g2 < 2; ++g2) {
      int col = j2 + g2 * 256;
#pragma unroll
      for (int p = 0; p < 2; ++p) {
        int d0 = kd + 2 * p, d1 = kd + 2 * p + 1;
        float a0 = d0 < 13 ? pa.wihx[((size_t)d * 512 + col) * 13 + d0] : (d0 == 15 ? pa.bs[d * 512 + col] : 0.f);
        float a1 = d1 < 13 ? pa.wihx[((size_t)d * 512 + col) * 13 + d1] : (d1 == 15 ? pa.bs[d * 512 + col] : 0.f);
        f16x2 ta; ta.x = (_Float16)a0; ta.y = (_Float16)a1;
        wxA[g2 * 2 + p] = ta;
        float b0 = d0 < 13 ? pb.wihx[((size_t)d * 512 + col) * 13 + d0] : (d0 == 15 ? pb.bs[d * 512 + col] : 0.f);
        float b1 = d1 < 13 ? pb.wihx[((size_t)d * 512 + col) * 13 + d1] : (d1 == 15 ? pb.bs[d * 512 + col] : 0.f);
        f16x2 tb; tb.x = (_Float16)b0; tb.y = (_Float16)b1;
        wxB[g2 * 2 + p] = tb;
      }
    }
#pragma unroll
    for (int i = 0; i < 4; ++i) { asm volatile("" : "+v"(wxA[i])); asm volatile("" : "+v"(wxB[i])); }
    // stage x row (packed f16, 16 dims: 13 real, 2 zero, x15=1 for bias)
    for (int i = tid; i < 4096; i += 1024) {
      int t_ = i >> 3, k_ = i & 7;
      int d0 = 2 * k_, d1 = 2 * k_ + 1;
      float v0 = d0 < 13 ? xin[((size_t)b * 512 + t_) * 13 + d0] : (d0 == 15 ? 1.f : 0.f);
      float v1 = d1 < 13 ? xin[((size_t)b * 512 + t_) * 13 + d1] : (d1 == 15 ? 1.f : 0.f);
      x_lds[i] = packh(v0, v1);
    }
  }

  const unsigned short* xga = FUSE ? (const unsigned short*)0
                                   : (const unsigned short*)pa.xg + ((size_t)(d * 128 + b)) * 262144;
  const unsigned short* xgb = (DUALB && !FUSE) ? (const unsigned short*)pb.xg + ((size_t)(d * 128 + b)) * 262144
                                               : (const unsigned short*)0;

  if (tid < 64) { hA[0][tid] = 0u; if (DUALB) hB[0][tid] = 0u; }
  float creg = 0.f, mreg = -1e30f;   // tid<128: layer A state; tid in [128,256): layer B
  int curA = 0, curB = 0;
  int tt0 = d ? 511 : 0;
  unsigned short pfa0 = 0, pfa1 = 0, pfb0 = 0, pfb1 = 0;
  if (!FUSE && kq == 0) {
    pfa0 = xga[(size_t)tt0 * 512 + j2];
    pfa1 = xga[(size_t)tt0 * 512 + j2 + 256];
    if (DUALB) {
      pfb0 = xgb[(size_t)tt0 * 512 + j2];
      pfb1 = xgb[(size_t)tt0 * 512 + j2 + 256];
    }
  }
  __syncthreads();

  for (int t = 0; t < 512; ++t) {
    int tt = d ? 511 - t : t;
    int tn = (t + 1 < 512) ? t + 1 : 511;
    int ttn = d ? 511 - tn : tn;

    // ---------------- phase alpha: dots_A(t) || cell_B(t-1) ----------------
    unsigned short pna0 = 0, pna1 = 0;
    if (!FUSE && kq == 0) {
      pna0 = xga[(size_t)ttn * 512 + j2];
      pna1 = xga[(size_t)ttn * 512 + j2 + 256];
    }
    {
      float s0, s1;
      DOT32(w16A, hA, curA, s0, s1);
      if (FUSE) {
        uint2 xv = *(const uint2*)&x_lds[tt * 8 + kq * 2];
        f16x2 x0 = h2bc(xv.x), x1 = h2bc(xv.y);
        s0 = FDOT2(wxA[0], x0, s0); s0 = FDOT2(wxA[1], x1, s0);
        s1 = FDOT2(wxA[2], x0, s1); s1 = FDOT2(wxA[3], x1, s1);
      } else if (kq == 0) {
        s0 += bfbits(pfa0); s1 += bfbits(pfa1);
      }
      pA[kq][j2] = s0;
      pA[kq][j2 + 256] = s1;
    }
    if (DUALB && t > 0 && tid >= 128 && tid < 256) {
      int ttpB = d ? 512 - t : t - 1;
      CELLPHASE(pb, tid - 128, pB, hB, curB ^ 1, ttpB);
    }
    __syncthreads();
    if (DUALB && t > 0) curB ^= 1;

    // ---------------- phase beta: dots_B(t) || cell_A(t) -------------------
    unsigned short pnb0 = 0, pnb1 = 0;
    if (DUALB) {
      if (!FUSE && kq == 0) {
        pnb0 = xgb[(size_t)ttn * 512 + j2];
        pnb1 = xgb[(size_t)ttn * 512 + j2 + 256];
      }
      float s0, s1;
      DOT32(w16B, hB, curB, s0, s1);
      if (FUSE) {
        uint2 xv = *(const uint2*)&x_lds[tt * 8 + kq * 2];
        f16x2 x0 = h2bc(xv.x), x1 = h2bc(xv.y);
        s0 = FDOT2(wxB[0], x0, s0); s0 = FDOT2(wxB[1], x1, s0);
        s1 = FDOT2(wxB[2], x0, s1); s1 = FDOT2(wxB[3], x1, s1);
      } else if (kq == 0) {
        s0 += bfbits(pfb0); s1 += bfbits(pfb1);
      }
      pB[kq][j2] = s0;
      pB[kq][j2 + 256] = s1;
    }
    if (tid < 128) {
      CELLPHASE(pa, tid, pA, hA, curA ^ 1, tt);
    }
    __syncthreads();
    curA ^= 1;
    pfa0 = pna0; pfa1 = pna1; pfb0 = pnb0; pfb1 = pnb1;
  }
  // epilogue: cell_B(511)
  if (DUALB && tid >= 128 && tid < 256) {
    int ttpB = d ? 0 : 511;
    CELLPHASE(pb, tid - 128, pB, hB, curB ^ 1, ttpB);
  }
  // maxpool outputs (d*128 offset REQUIRED — R3 lesson)
  if (!pa.yout && tid < 128)
    pa.y3out[(size_t)b * 512 + pa.y3off + d * 128 + tid] = mreg;
  if (DUALB && !pb.yout && tid >= 128 && tid < 256)
    pb.y3out[(size_t)b * 512 + pb.y3off + d * 128 + (tid - 128)] = mreg;
}

// ---------------------------------------------------------------------------
// Head: y4 = selu(y3 @ l4w^T + l4b); out = sigmoid(y4 @ fcw^T + fcb).
// ---------------------------------------------------------------------------
__global__ __launch_bounds__(256) void head(
    const float* __restrict__ y3, const float* __restrict__ l4w,
    const float* __restrict__ l4b, const float* __restrict__ fcw,
    const float* __restrict__ fcb, float* __restrict__ outp)
{
  int b = blockIdx.x, t = threadIdx.x;
  __shared__ float row[512];
  __shared__ float y4[128];
  row[t] = y3[(size_t)b * 512 + t];
  row[t + 256] = y3[(size_t)b * 512 + t + 256];
  __syncthreads();
  if (t < 128) {
    float acc = l4b[t];
    const float* wr = l4w + (size_t)t * 512;
    for (int k = 0; k < 512; ++k) acc += row[k] * wr[k];
    const float scale = 1.0507009873554804934193349852946f;
    const float alpha = 1.6732632423543772848170429916717f;
    y4[t] = acc > 0.f ? scale * acc : scale * alpha * (__expf(acc) - 1.f);
  }
  __syncthreads();
  if (t < 2) {
    float acc = fcb[t];
    const float* wr = fcw + (size_t)t * 128;
    for (int k = 0; k < 128; ++k) acc += y4[k] * wr[k];
    outp[b * 2 + t] = 1.f / (1.f + __expf(-acc));
  }
}

extern "C" void kernel_launch(void* const* d_in, const int* in_sizes, int n_in,
                              void* d_out, int out_size, void* d_ws, size_t ws_size,
                              hipStream_t stream) {
  (void)in_sizes; (void)n_in; (void)out_size;
  const float* x     = (const float*)d_in[0];
  const float* Wih1  = (const float*)d_in[1];
  const float* Whh1  = (const float*)d_in[2];
  const float* bih1  = (const float*)d_in[3];
  const float* bhh1  = (const float*)d_in[4];
  const float* Wih21 = (const float*)d_in[5];
  const float* Whh21 = (const float*)d_in[6];
  const float* bih21 = (const float*)d_in[7];
  const float* bhh21 = (const float*)d_in[8];
  const float* Wih22 = (const float*)d_in[9];
  const float* Whh22 = (const float*)d_in[10];
  const float* bih22 = (const float*)d_in[11];
  const float* bhh22 = (const float*)d_in[12];
  const float* Wih31 = (const float*)d_in[13];
  const float* Whh31 = (const float*)d_in[14];
  const float* bih31 = (const float*)d_in[15];
  const float* bhh31 = (const float*)d_in[16];
  const float* Wih32 = (const float*)d_in[17];
  const float* Whh32 = (const float*)d_in[18];
  const float* bih32 = (const float*)d_in[19];
  const float* bhh32 = (const float*)d_in[20];
  const float* l4w   = (const float*)d_in[21];
  const float* l4b   = (const float*)d_in[22];
  const float* fcw   = (const float*)d_in[23];
  const float* fcb   = (const float*)d_in[24];

  char* ws = (char*)d_ws;
  const size_t NEED_F31 = 340545536ull;
  bool f31 = (ws_size >= NEED_F31);

  __hip_bfloat16 *xgA, *xgB, *y1, *y2, *wihbf;
  float *y3, *bsum, *whht;
  if (f31) {
    xgA   = (__hip_bfloat16*)(ws);
    xgB   = (__hip_bfloat16*)(ws + 134217728);
    y1    = (__hip_bfloat16*)(ws + 134217728);   // alias xgB head: dead before proj32 writes xgB
    y2    = (__hip_bfloat16*)(ws + 268435456);
    y3    = (float*)(ws + 335544320);
    wihbf = (__hip_bfloat16*)(ws + 335806464);
    bsum  = (float*)(ws + 337903616);
    whht  = (float*)(ws + 337924096);            // end 340545536
  } else {
    xgA   = (__hip_bfloat16*)(ws);
    xgB   = xgA;
    y1    = (__hip_bfloat16*)(ws + 134217728);
    y2    = (__hip_bfloat16*)(ws + 167772160);
    y3    = (float*)(ws + 234881024);
    wihbf = (__hip_bfloat16*)(ws + 235143168);
    bsum  = (float*)(ws + 237240320);
    whht  = (float*)(ws + 237260800);            // end ~239.9 MB (proven fits)
  }

  wconv<<<6676, 256, 0, stream>>>(Whh1, Whh21, Whh22, Whh31, Whh32,
                                  Wih21, Wih31, Wih32,
                                  bih1, bhh1, bih21, bhh21, bih22, bhh22,
                                  bih31, bhh31, bih32, bhh32,
                                  whht, wihbf, bsum);

  ScanP P1  = {nullptr, Wih1,  bsum + 0 * 1024, whht + 0 * 131072, y1, 256, 0,   nullptr, 0};
  ScanP P22 = {nullptr, Wih22, bsum + 2 * 1024, whht + 2 * 131072, y2, 512, 256, nullptr, 0};
  ScanP P21 = {xgA, nullptr, nullptr, whht + 1 * 131072, y2, 512, 0, nullptr, 0};
  ScanP P31 = {xgA, nullptr, nullptr, whht + 3 * 131072, nullptr, 0, 0, y3, 0};
  ScanP P32 = {xgB, nullptr, nullptr, whht + 4 * 131072, nullptr, 0, 0, y3, 256};

  // layers 1 || 22, input proj fused in-kernel (no xg)
  scan7<true, true><<<dim3(128, 2), 1024, 0, stream>>>(P1, P22, x);
  // layer 21
  projM<<<dim3(4, 512, 2), 256, 0, stream>>>(y1, 256, 256, wihbf + 0, bsum + 1 * 1024, xgA);
  scan7<false, false><<<dim3(128, 2), 1024, 0, stream>>>(P21, P21, nullptr);
  if (f31) {
    // layers 31 || 32 (two xg buffers)
    projM<<<dim3(4, 512, 2), 256, 0, stream>>>(y2, 512, 512, wihbf + 262144, bsum + 3 * 1024, xgA);
    projM<<<dim3(4, 512, 2), 256, 0, stream>>>(y2, 512, 256, wihbf + 786432, bsum + 4 * 1024, xgB);
    scan7<true, false><<<dim3(128, 2), 1024, 0, stream>>>(P31, P32, nullptr);
  } else {
    projM<<<dim3(4, 512, 2), 256, 0, stream>>>(y2, 512, 512, wihbf + 262144, bsum + 3 * 1024, xgA);
    scan7<false, false><<<dim3(128, 2), 1024, 0, stream>>>(P31, P31, nullptr);
    projM<<<dim3(4, 512, 2), 256, 0, stream>>>(y2, 512, 256, wihbf + 786432, bsum + 4 * 1024, xgA);
    scan7<false, false><<<dim3(128, 2), 1024, 0, stream>>>(P32, P32, nullptr);
  }
  head<<<128, 256, 0, stream>>>(y3, l4w, l4b, fcw, fcb, (float*)d_out);
}